// Round 11
// baseline (369.859 us; speedup 1.0000x reference)
//
#include <hip/hip_runtime.h>

#define B 100
#define R 1152
#define C 10
#define O 16
#define I 8
#define RI 9216
#define RC2 2304        // x0 row length in float4
#define RCHUNK 48
#define NRC 24          // R / RCHUNK
#define KCH 384         // RCHUNK*I

#define T1c (-0.075410217f)
#define T3c (0.062207676f)

typedef float f4raw __attribute__((ext_vector_type(4)));
static __device__ __forceinline__ void nt_store4(const float4& v, float4* p) {
    __builtin_nontemporal_store(*(const f4raw*)&v, (f4raw*)p);
}

// ws float offsets
#define WS_BCOL 0                  // [c][r] 11520
#define WS_CSM  11520              // [r][c] 11520
#define WS_PART 23040              // [c][24][100][16] = 384000
#define WS_PARTF 407040            // [c][24][100] = 24000

// out float4 offsets
#define O_VJ 0
#define O_CF 4000
#define O_WB 292000
#define O_SQ 37156000
#define O_X1 39460000
#define O_X2 39690400
#define O_SM 39710000

// static stream units (80KB each): Wb 7200 | squashed_u 563 | x1 57 | x2 5
#define U_WB 7200
#define U_SQ 563
#define U_X1 57
#define U_TOT 7825

__device__ void stream_unit(int u, const float4* __restrict__ W4,
                            const float4* __restrict__ x04,
                            const float4* __restrict__ x14,
                            const float4* __restrict__ x24,
                            float4* __restrict__ out) {
    const int t = threadIdx.x;
    if (u < U_WB) {
        int wchunk = u % 1440, bg = u / 1440;
        int idx = wchunk * 256 + t;
        float4 v = W4[idx];
        float4* dst = out + O_WB + (size_t)bg * 20 * 368640 + idx;
        #pragma unroll
        for (int b = 0; b < 20; b++) { nt_store4(v, dst); dst += 368640; }
    } else if (u < U_WB + U_SQ) {
        int s = u - U_WB;
        int m0 = s * 4096, m1 = m0 + 4096; if (m1 > 2304000) m1 = 2304000;
        for (int m = m0 + t; m < m1; m += 256) {
            float4 v = x04[(m / 20) * 2 + (m & 1)];   // squashed_u = x0 bcast over c
            nt_store4(v, &out[O_SQ + m]);
        }
    } else if (u < U_WB + U_SQ + U_X1) {
        int s = u - U_WB - U_SQ;
        int m0 = s * 4096, m1 = m0 + 4096; if (m1 > 230400) m1 = 230400;
        for (int m = m0 + t; m < m1; m += 256) nt_store4(x14[m], &out[O_X1 + m]);
    } else {
        int s = u - U_WB - U_SQ - U_X1;
        int m0 = s * 4096, m1 = m0 + 4096; if (m1 > 19600) m1 = 19600;
        for (int m = m0 + t; m < m1; m += 256) nt_store4(x24[m], &out[O_X2 + m]);
    }
}

// ---------- G: s_j partial GEMM (NRC=24), softmax fused; writes PART + PARTF ----------
__global__ __launch_bounds__(256) void k_gemm(const float* __restrict__ Wg,
                                              const float* __restrict__ x0,
                                              float* __restrict__ ws,
                                              const float4* __restrict__ x14,
                                              const float4* __restrict__ x24,
                                              float4* __restrict__ out,
                                              int it, int ubase) {
    const int t = threadIdx.x;
    const float4* x04 = (const float4*)x0;
    if (blockIdx.x >= 240) {
        stream_unit(ubase + (blockIdx.x - 240), (const float4*)Wg, x04, x14, x24, out);
        return;
    }
    const int rc = blockIdx.x % NRC, c = blockIdx.x / NRC;
    const int r0 = rc * RCHUNK;
    __shared__ float red[256];
    __shared__ float cw[RCHUNK];
    __shared__ __align__(16) float lw[KCH * O];   // 6144: [k][o], c-weight folded
    __shared__ float2 tpp[16][104];               // [kpair][b] per 32-k phase; 13.3 KB

    if (it > 0) {
        const float* bcol = ws + WS_BCOL + c * R;
        float lm = -3.4e38f;
        for (int r = t; r < R; r += 256) lm = fmaxf(lm, bcol[r]);
        red[t] = lm; __syncthreads();
        for (int s = 128; s > 0; s >>= 1) { if (t < s) red[t] = fmaxf(red[t], red[t + s]); __syncthreads(); }
        const float m = red[0]; __syncthreads();
        float ls = 0.f;
        for (int r = t; r < R; r += 256) ls += expf(bcol[r] - m);
        red[t] = ls; __syncthreads();
        for (int s = 128; s > 0; s >>= 1) { if (t < s) red[t] += red[t + s]; __syncthreads(); }
        const float sinv = 1.f / red[0];
        if (t < RCHUNK) cw[t] = expf(bcol[r0 + t] - m) * sinv;
        if (it == 2 && rc == 0) {   // final c_ij feeds the c_full output
            for (int r = t; r < R; r += 256)
                ws[WS_CSM + r * C + c] = expf(bcol[r] - m) * sinv;
        }
    } else {
        if (t < RCHUNK) cw[t] = 1.0f / 1152.0f;   // softmax of zeros
    }
    __syncthreads();

    // stage c-weighted W slice (once): lw[(rr*8+i)*16+o] = cw[rr]*W[r0+rr,c,o,i]
    for (int j = t; j < KCH * O; j += 256) {
        int rr = j >> 7;
        int rem = j & 127;            // o*8+i
        int o = rem >> 3, i = rem & 7;
        lw[((rr * I + i) << 4) + o] = cw[rr] * Wg[((size_t)(r0 + rr) * C + c) * 128 + rem];
    }

    const int bl = t & 63, og = t >> 6;
    int b2 = bl + 64; if (b2 > 103) b2 = 103;    // clamps into zero pad
    float4 a0 = {0, 0, 0, 0}, a1 = {0, 0, 0, 0};
    for (int p = 0; p < 12; p++) {
        __syncthreads();   // covers lw staging (p0) / prev-phase reads
        int colbase = r0 * 2 + p * 8;            // 8 f4 (=32 k) per phase
        for (int e = t; e < 800; e += 256) {
            int b = e >> 3, q = e & 7;
            float4 v = x04[(size_t)b * RC2 + colbase + q];
            tpp[q * 2 + 0][b] = make_float2(v.x, v.y);
            tpp[q * 2 + 1][b] = make_float2(v.z, v.w);
        }
        if (p == 0 && t < 64) tpp[t >> 2][100 + (t & 3)] = make_float2(0.f, 0.f);
        __syncthreads();
        const float4* lwp = (const float4*)lw + p * 128;
        #pragma unroll 8
        for (int k2 = 0; k2 < 16; k2++) {
            float2 xv0 = tpp[k2][bl];
            float2 xv1 = tpp[k2][b2];
            float4 wa = lwp[k2 * 8 + og];
            float4 wb = lwp[k2 * 8 + 4 + og];
            a0.x += xv0.x * wa.x + xv0.y * wb.x;
            a0.y += xv0.x * wa.y + xv0.y * wb.y;
            a0.z += xv0.x * wa.z + xv0.y * wb.z;
            a0.w += xv0.x * wa.w + xv0.y * wb.w;
            a1.x += xv1.x * wa.x + xv1.y * wb.x;
            a1.y += xv1.x * wa.y + xv1.y * wb.y;
            a1.z += xv1.x * wa.z + xv1.y * wb.z;
            a1.w += xv1.x * wa.w + xv1.y * wb.w;
        }
    }
    float4* part4 = (float4*)(ws + WS_PART);
    int base = ((c * NRC + rc) * B + bl) * 4 + og;
    part4[base] = a0;
    if (bl < 36) part4[base + 256] = a1;
    if (og == 0) {   // packed f-plane (o=0) for squash
        ws[WS_PARTF + (c * NRC + rc) * B + bl] = a0.x;
        if (bl < 36) ws[WS_PARTF + (c * NRC + rc) * B + bl + 64] = a1.x;
    }
}

// ---------- A: self-contained squash + agreement; 36 r-groups x 5 c-pairs ----------
__global__ __launch_bounds__(256) void k_agree(const float* __restrict__ Wg,
                                               const float* __restrict__ x0,
                                               float* __restrict__ ws,
                                               const float4* __restrict__ x14,
                                               const float4* __restrict__ x24,
                                               float4* __restrict__ out,
                                               int it, int ubase) {
    const int t = threadIdx.x;
    if (blockIdx.x >= 180) {
        stream_unit(ubase + (blockIdx.x - 180), (const float4*)Wg, (const float4*)x0, x14, x24, out);
        return;
    }
    const int rg = blockIdx.x / 5, ch = blockIdx.x % 5;
    const int rbase = rg * 32;
    __shared__ float fs[1000];                 // f[c][b], all c (squash needs all)
    __shared__ float nf2[200];                 // new_f for this block's 2 c's
    __shared__ __align__(16) float vt[3200];   // v[cc][b], cc = (c_local*16+o)
    __shared__ __align__(16) float xs[800];    // [i][b]
    __shared__ __align__(16) float arr[256];   // [co][i]
    const float4* x04 = (const float4*)x0;

    // f = reduce PARTF over rc
    for (int j = t; j < 1000; j += 256) {
        int c = j / 100, b = j - c * 100;
        const float* p = ws + WS_PARTF + c * (NRC * B) + b;
        float s = 0.f;
        #pragma unroll 8
        for (int rc = 0; rc < NRC; rc++) s += p[rc * B];
        fs[j] = s;
    }
    __syncthreads();
    // squash (exact reference semantics) for the 2 local c's
    if (t < 200) {
        int cl = t / 100, b = t - cl * 100;
        int c = ch * 2 + cl;
        float mine = fs[c * 100 + b];
        int rank = 0, i1 = 0, i2 = 0, i3 = 0;
        #pragma unroll
        for (int c2 = 0; c2 < C; c2++) {
            float f2 = fs[c2 * 100 + b];
            rank += (f2 < mine) || (f2 == mine && c2 < c);
            i1 += f2 < T1c;
            i2 += f2 < 0.0f;
            i3 += f2 < T3c;
        }
        float nv = mine;
        if (i1 > 0 && rank < i1 - 1)                               nv = -0.074520095f * mine + 0.349297946f;
        else if (i2 > 0 && i2 > i1 && rank >= i1 && rank < i2 - 1) nv = -0.534473989f * mine + 0.27196494f;
        else if (i3 > 0 && i3 > i2 && rank >= i2 && rank < i3 - 1) nv = 0.637642944f * mine + 0.295330779f;
        else if (i3 < C && rank >= i3 && rank < C - 1)             nv = 0.169344703f * mine + 0.353784456f;
        nf2[t] = nv;
    }
    __syncthreads();
    // vt = v[b][c][o] for the 2 local c's, reduced from PART
    for (int j = t; j < 3200; j += 256) {
        int cl = j / 1600, rem = j - cl * 1600;
        int b = rem >> 4, o = rem & 15;
        int c = ch * 2 + cl;
        const float* p = ws + WS_PART + (size_t)(c * NRC) * 1600 + b * 16 + o;
        float s = 0.f;
        #pragma unroll 8
        for (int rc = 0; rc < NRC; rc++) s += p[rc * 1600];
        float nfv = nf2[cl * 100 + b];
        float smut = (o == 0) ? nfv : s;
        vt[(cl * 16 + o) * 100 + b] = nfv * smut;
    }

    const int i = t & 7, co = t >> 3;         // co in [0,32)
    const float4* xs4 = (const float4*)(xs + i * B);
    const float4* vt4 = (const float4*)(vt + co * B);
    const int cg = ch * 2 + (co >> 4), og = co & 15;
    for (int rr = 0; rr < 32; rr++) {
        const int r = rbase + rr;
        __syncthreads();   // protects xs/arr reuse (first pass: vt writes)
        if (t < 200) {
            int b = t >> 1, half = t & 1;
            float4 v = x04[(size_t)b * RC2 + r * 2 + half];
            xs[(half * 4 + 0) * B + b] = v.x; xs[(half * 4 + 1) * B + b] = v.y;
            xs[(half * 4 + 2) * B + b] = v.z; xs[(half * 4 + 3) * B + b] = v.w;
        }
        __syncthreads();
        float q = 0.f;
        #pragma unroll
        for (int b4 = 0; b4 < 25; b4++) {
            float4 xv = xs4[b4];
            float4 vv = vt4[b4];
            q += xv.x * vv.x + xv.y * vv.y + xv.z * vv.z + xv.w * vv.w;
        }
        arr[co * I + i] = q * Wg[(size_t)r * 1280 + (cg * 16 + og) * 8 + i];
        __syncthreads();
        if (t < 2) {
            const float4* a4 = (const float4*)(arr + t * 128);
            float d = 0.f;
            #pragma unroll
            for (int m2 = 0; m2 < 32; m2++) { float4 v4 = a4[m2]; d += v4.x + v4.y + v4.z + v4.w; }
            float* dst = ws + WS_BCOL + (ch * 2 + t) * R + r;
            float val = d * (1.0f / B);
            if (it == 0) *dst = val; else *dst += val;
        }
    }
}

// ---------- OUT: final squash (blocks 0..99) + c_full + bulk stream units ----------
__global__ __launch_bounds__(256) void k_out(const float* __restrict__ x0,
                                             const float* __restrict__ x1,
                                             const float* __restrict__ x2,
                                             float* __restrict__ ws,
                                             const float* __restrict__ Wg,
                                             float4* __restrict__ out) {
    const int bid = blockIdx.x, t = threadIdx.x;
    if (bid < B) {   // final squash from G2 partials -> v_j + s_mut straight to out
        const int b = bid;
        __shared__ float sl[160];
        __shared__ float nf[C];
        __shared__ __align__(16) float vv[160];
        __shared__ __align__(16) float sm[160];
        if (t < 160) {
            int c = t >> 4, o = t & 15;
            float s = 0.f;
            const float* p = ws + WS_PART + ((size_t)c * NRC * B + b) * 16 + o;
            #pragma unroll 8
            for (int rc = 0; rc < NRC; rc++) s += p[rc * 1600];
            sl[t] = s;
        }
        __syncthreads();
        if (t < C) {
            float fv[C];
            #pragma unroll
            for (int c2 = 0; c2 < C; c2++) fv[c2] = sl[c2 * O];
            float mine = sl[t * O];
            int rank = 0, i1 = 0, i2 = 0, i3 = 0;
            #pragma unroll
            for (int c2 = 0; c2 < C; c2++) {
                rank += (fv[c2] < mine) || (fv[c2] == mine && c2 < t);
                i1 += fv[c2] < T1c;
                i2 += fv[c2] < 0.0f;
                i3 += fv[c2] < T3c;
            }
            float nv = mine;
            if (i1 > 0 && rank < i1 - 1)                               nv = -0.074520095f * mine + 0.349297946f;
            else if (i2 > 0 && i2 > i1 && rank >= i1 && rank < i2 - 1) nv = -0.534473989f * mine + 0.27196494f;
            else if (i3 > 0 && i3 > i2 && rank >= i2 && rank < i3 - 1) nv = 0.637642944f * mine + 0.295330779f;
            else if (i3 < C && rank >= i3 && rank < C - 1)             nv = 0.169344703f * mine + 0.353784456f;
            nf[t] = nv;
        }
        __syncthreads();
        if (t < 160) {
            int c = t >> 4, o = t & 15;
            float smut = (o == 0) ? nf[c] : sl[t];
            sm[t] = smut;
            vv[t] = nf[c] * smut;
        }
        __syncthreads();
        if (t < 40) {
            nt_store4(((const float4*)vv)[t], &out[O_VJ + b * 40 + t]);
            nt_store4(((const float4*)sm)[t], &out[O_SM + b * 40 + t]);
        }
    }
    // c_full (CSM repeated per b)
    const float4* cs4 = (const float4*)(ws + WS_CSM);
    for (int j = bid * 256 + t; j < 288000; j += 2048 * 256)
        nt_store4(cs4[j % 2880], &out[O_CF + j]);
    // remaining stream units (4080..7824)
    for (int k = 0; k < 2; k++) {
        int u = 4080 + bid + k * 2048;
        if (u < U_TOT)
            stream_unit(u, (const float4*)Wg, (const float4*)x0,
                        (const float4*)x1, (const float4*)x2, out);
    }
}

extern "C" void kernel_launch(void* const* d_in, const int* in_sizes, int n_in,
                              void* d_out, int out_size, void* d_ws, size_t ws_size,
                              hipStream_t stream) {
    (void)in_sizes; (void)n_in; (void)out_size; (void)ws_size;
    const float* x0 = (const float*)d_in[0];
    const float* x1 = (const float*)d_in[1];
    const float* x2 = (const float*)d_in[2];
    const float* Wg = (const float*)d_in[3];
    const float4* x14 = (const float4*)x1;
    const float4* x24 = (const float4*)x2;
    float* ws = (float*)d_ws;
    float4* out = (float4*)d_out;

    // 6 launches, 5 boundaries. Riders capped to single-round co-residency:
    // G 4 blocks/CU (39KB LDS) -> 240+760 <= 1024; A 6/CU -> 180+900 <= 1536.
    // unit bases: G0=0(760) A0=760(900) G1=1660(760) A1=2420(900) G2=3320(760);
    // k_out drains 4080..7824.
    hipLaunchKernelGGL(k_gemm,  dim3(240 + 760), dim3(256), 0, stream, Wg, x0, ws, x14, x24, out, 0, 0);
    hipLaunchKernelGGL(k_agree, dim3(180 + 900), dim3(256), 0, stream, Wg, x0, ws, x14, x24, out, 0, 760);
    hipLaunchKernelGGL(k_gemm,  dim3(240 + 760), dim3(256), 0, stream, Wg, x0, ws, x14, x24, out, 1, 1660);
    hipLaunchKernelGGL(k_agree, dim3(180 + 900), dim3(256), 0, stream, Wg, x0, ws, x14, x24, out, 1, 2420);
    hipLaunchKernelGGL(k_gemm,  dim3(240 + 760), dim3(256), 0, stream, Wg, x0, ws, x14, x24, out, 2, 3320);
    hipLaunchKernelGGL(k_out,   dim3(2048), dim3(256), 0, stream, x0, x1, x2, ws, Wg, out);
}

// Round 12
// 266.851 us; speedup vs baseline: 1.3860x; 1.3860x over previous
//
#include <hip/hip_runtime.h>

#define B 100
#define R 1152
#define C 10
#define O 16
#define I 8
#define RI 9216
#define RC2 2304        // x0 row length in float4
#define RCHUNK 48
#define NRC 24          // R / RCHUNK
#define KCH 384         // RCHUNK*I

#define T1c (-0.075410217f)
#define T3c (0.062207676f)

typedef float f4raw __attribute__((ext_vector_type(4)));
static __device__ __forceinline__ void nt_store4(const float4& v, float4* p) {
    __builtin_nontemporal_store(*(const f4raw*)&v, (f4raw*)p);
}

// ws float offsets
#define WS_BCOL 0                  // [c][r] 11520
#define WS_CSM  11520              // [r][c] 11520
#define WS_PART 23040              // [c][24][100][16] = 384000
#define WS_PARTF 407040            // [c][24][100] = 24000

// out float4 offsets
#define O_VJ 0
#define O_CF 4000
#define O_WB 292000
#define O_SQ 37156000
#define O_X1 39460000
#define O_X2 39690400
#define O_SM 39710000

// static stream units (80KB each): Wb 7200 | squashed_u 563 | x1 57 | x2 5
#define U_WB 7200
#define U_SQ 563
#define U_X1 57
#define U_TOT 7825

__device__ void stream_unit(int u, const float4* __restrict__ W4,
                            const float4* __restrict__ x04,
                            const float4* __restrict__ x14,
                            const float4* __restrict__ x24,
                            float4* __restrict__ out) {
    const int t = threadIdx.x;
    if (u < U_WB) {
        int wchunk = u % 1440, bg = u / 1440;
        int idx = wchunk * 256 + t;
        float4 v = W4[idx];
        float4* dst = out + O_WB + (size_t)bg * 20 * 368640 + idx;
        #pragma unroll
        for (int b = 0; b < 20; b++) { nt_store4(v, dst); dst += 368640; }
    } else if (u < U_WB + U_SQ) {
        int s = u - U_WB;
        int m0 = s * 4096, m1 = m0 + 4096; if (m1 > 2304000) m1 = 2304000;
        for (int m = m0 + t; m < m1; m += 256) {
            float4 v = x04[(m / 20) * 2 + (m & 1)];   // squashed_u = x0 bcast over c
            nt_store4(v, &out[O_SQ + m]);
        }
    } else if (u < U_WB + U_SQ + U_X1) {
        int s = u - U_WB - U_SQ;
        int m0 = s * 4096, m1 = m0 + 4096; if (m1 > 230400) m1 = 230400;
        for (int m = m0 + t; m < m1; m += 256) nt_store4(x14[m], &out[O_X1 + m]);
    } else {
        int s = u - U_WB - U_SQ - U_X1;
        int m0 = s * 4096, m1 = m0 + 4096; if (m1 > 19600) m1 = 19600;
        for (int m = m0 + t; m < m1; m += 256) nt_store4(x24[m], &out[O_X2 + m]);
    }
}

// ---------- G: s_j partial GEMM (NRC=24), softmax fused; writes PART + PARTF ----------
__global__ __launch_bounds__(256) void k_gemm(const float* __restrict__ Wg,
                                              const float* __restrict__ x0,
                                              float* __restrict__ ws,
                                              const float4* __restrict__ x14,
                                              const float4* __restrict__ x24,
                                              float4* __restrict__ out,
                                              int it, int ubase) {
    const int t = threadIdx.x;
    const float4* x04 = (const float4*)x0;
    if (blockIdx.x >= 240) {
        stream_unit(ubase + (blockIdx.x - 240), (const float4*)Wg, x04, x14, x24, out);
        return;
    }
    const int rc = blockIdx.x % NRC, c = blockIdx.x / NRC;
    const int r0 = rc * RCHUNK;
    __shared__ float red[256];
    __shared__ float cw[RCHUNK];
    __shared__ __align__(16) float lw[KCH * O];   // 6144: [k][o], c-weight folded
    __shared__ float2 tpp[16][104];               // [kpair][b] per 32-k phase; 13.3 KB

    if (it > 0) {
        const float* bcol = ws + WS_BCOL + c * R;
        float lm = -3.4e38f;
        for (int r = t; r < R; r += 256) lm = fmaxf(lm, bcol[r]);
        red[t] = lm; __syncthreads();
        for (int s = 128; s > 0; s >>= 1) { if (t < s) red[t] = fmaxf(red[t], red[t + s]); __syncthreads(); }
        const float m = red[0]; __syncthreads();
        float ls = 0.f;
        for (int r = t; r < R; r += 256) ls += expf(bcol[r] - m);
        red[t] = ls; __syncthreads();
        for (int s = 128; s > 0; s >>= 1) { if (t < s) red[t] += red[t + s]; __syncthreads(); }
        const float sinv = 1.f / red[0];
        if (t < RCHUNK) cw[t] = expf(bcol[r0 + t] - m) * sinv;
        if (it == 2 && rc == 0) {   // final c_ij feeds the c_full output
            for (int r = t; r < R; r += 256)
                ws[WS_CSM + r * C + c] = expf(bcol[r] - m) * sinv;
        }
    } else {
        if (t < RCHUNK) cw[t] = 1.0f / 1152.0f;   // softmax of zeros
    }
    __syncthreads();

    // stage c-weighted W slice (once): lw[(rr*8+i)*16+o] = cw[rr]*W[r0+rr,c,o,i]
    for (int j = t; j < KCH * O; j += 256) {
        int rr = j >> 7;
        int rem = j & 127;            // o*8+i
        int o = rem >> 3, i = rem & 7;
        lw[((rr * I + i) << 4) + o] = cw[rr] * Wg[((size_t)(r0 + rr) * C + c) * 128 + rem];
    }

    const int bl = t & 63, og = t >> 6;
    int b2 = bl + 64; if (b2 > 103) b2 = 103;    // clamps into zero pad
    float4 a0 = {0, 0, 0, 0}, a1 = {0, 0, 0, 0};
    for (int p = 0; p < 12; p++) {
        __syncthreads();   // covers lw staging (p0) / prev-phase reads
        int colbase = r0 * 2 + p * 8;            // 8 f4 (=32 k) per phase
        for (int e = t; e < 800; e += 256) {
            int b = e >> 3, q = e & 7;
            float4 v = x04[(size_t)b * RC2 + colbase + q];
            tpp[q * 2 + 0][b] = make_float2(v.x, v.y);
            tpp[q * 2 + 1][b] = make_float2(v.z, v.w);
        }
        if (p == 0 && t < 64) tpp[t >> 2][100 + (t & 3)] = make_float2(0.f, 0.f);
        __syncthreads();
        const float4* lwp = (const float4*)lw + p * 128;
        #pragma unroll 8
        for (int k2 = 0; k2 < 16; k2++) {
            float2 xv0 = tpp[k2][bl];
            float2 xv1 = tpp[k2][b2];
            float4 wa = lwp[k2 * 8 + og];
            float4 wb = lwp[k2 * 8 + 4 + og];
            a0.x += xv0.x * wa.x + xv0.y * wb.x;
            a0.y += xv0.x * wa.y + xv0.y * wb.y;
            a0.z += xv0.x * wa.z + xv0.y * wb.z;
            a0.w += xv0.x * wa.w + xv0.y * wb.w;
            a1.x += xv1.x * wa.x + xv1.y * wb.x;
            a1.y += xv1.x * wa.y + xv1.y * wb.y;
            a1.z += xv1.x * wa.z + xv1.y * wb.z;
            a1.w += xv1.x * wa.w + xv1.y * wb.w;
        }
    }
    float4* part4 = (float4*)(ws + WS_PART);
    int base = ((c * NRC + rc) * B + bl) * 4 + og;
    part4[base] = a0;
    if (bl < 36) part4[base + 256] = a1;
    if (og == 0) {   // packed f-plane (o=0) for squash
        ws[WS_PARTF + (c * NRC + rc) * B + bl] = a0.x;
        if (bl < 36) ws[WS_PARTF + (c * NRC + rc) * B + bl + 64] = a1.x;
    }
}

// ---------- A': fused squash + agreement; 720 blocks (72 rgroups x 10 c) ----------
__global__ __launch_bounds__(256) void k_agree(const float* __restrict__ Wg,
                                               const float* __restrict__ x0,
                                               float* __restrict__ ws,
                                               const float4* __restrict__ x14,
                                               const float4* __restrict__ x24,
                                               float4* __restrict__ out,
                                               int it, int ubase) {
    const int t = threadIdx.x;
    if (blockIdx.x >= 720) {
        stream_unit(ubase + (blockIdx.x - 720), (const float4*)Wg, (const float4*)x0, x14, x24, out);
        return;
    }
    const int rg = blockIdx.x / 10, c = blockIdx.x % 10;
    const int rbase = rg * 16;
    __shared__ float fs[1000];                  // f[c2][b], all classes
    __shared__ float nf1[100];                  // new_f for this block's c
    __shared__ __align__(16) float vt[1600];    // v[o][b] for this c
    __shared__ __align__(16) float xs[1600];    // [rl][i][b], 2 r's
    __shared__ float red2[4];
    const float4* x04 = (const float4*)x0;

    // phase 1: fs = reduce PARTF over rc (L2-resident, coalesced)
    for (int j = t; j < 1000; j += 256) {
        int c2 = j / 100, b = j - c2 * 100;
        const float* p = ws + WS_PARTF + c2 * (NRC * B) + b;
        float s = 0.f;
        #pragma unroll 8
        for (int rc = 0; rc < NRC; rc++) s += p[rc * B];
        fs[j] = s;
    }
    __syncthreads();
    // phase 2: exact squash for this c
    if (t < 100) {
        int b = t;
        float mine = fs[c * 100 + b];
        int rank = 0, i1 = 0, i2 = 0, i3 = 0;
        #pragma unroll
        for (int c2 = 0; c2 < C; c2++) {
            float f2 = fs[c2 * 100 + b];
            rank += (f2 < mine) || (f2 == mine && c2 < c);
            i1 += f2 < T1c;
            i2 += f2 < 0.0f;
            i3 += f2 < T3c;
        }
        float nv = mine;
        if (i1 > 0 && rank < i1 - 1)                               nv = -0.074520095f * mine + 0.349297946f;
        else if (i2 > 0 && i2 > i1 && rank >= i1 && rank < i2 - 1) nv = -0.534473989f * mine + 0.27196494f;
        else if (i3 > 0 && i3 > i2 && rank >= i2 && rank < i3 - 1) nv = 0.637642944f * mine + 0.295330779f;
        else if (i3 < C && rank >= i3 && rank < C - 1)             nv = 0.169344703f * mine + 0.353784456f;
        nf1[b] = nv;
    }
    __syncthreads();
    // phase 3: vt[o][b] = nf * smut, reduced from this c's PART slice (coalesced)
    for (int j = t; j < 1600; j += 256) {
        int b = j >> 4, o = j & 15;
        const float* p = ws + WS_PART + (size_t)c * (NRC * 1600) + b * 16 + o;
        float s = 0.f;
        #pragma unroll 8
        for (int rc = 0; rc < NRC; rc++) s += p[rc * 1600];
        float nfv = nf1[b];
        float smut = (o == 0) ? nfv : s;
        vt[o * 100 + b] = nfv * smut;
    }

    // phase 4: 8 iterations x 2 r's; full-wave shfl reductions
    const int rl = t >> 7, o = (t >> 3) & 15, i = t & 7;
    const float4* vt4 = (const float4*)(vt + o * 100);
    const float4* xs4 = (const float4*)(xs + rl * 800 + i * 100);
    for (int m = 0; m < 8; m++) {
        __syncthreads();   // protects xs (and vt on first iter)
        if (t < 200) {
            int b = t % 100, rl2 = t / 100;
            int r = rbase + m * 2 + rl2;
            float4 v0 = x04[(size_t)b * RC2 + r * 2];
            float4 v1 = x04[(size_t)b * RC2 + r * 2 + 1];
            float* xp = xs + rl2 * 800;
            xp[0 * 100 + b] = v0.x; xp[1 * 100 + b] = v0.y;
            xp[2 * 100 + b] = v0.z; xp[3 * 100 + b] = v0.w;
            xp[4 * 100 + b] = v1.x; xp[5 * 100 + b] = v1.y;
            xp[6 * 100 + b] = v1.z; xp[7 * 100 + b] = v1.w;
        }
        __syncthreads();
        const int r = rbase + m * 2 + rl;
        float q = 0.f;
        #pragma unroll
        for (int b4 = 0; b4 < 25; b4++) {
            float4 xv = xs4[b4];
            float4 vv = vt4[b4];
            q += xv.x * vv.x + xv.y * vv.y + xv.z * vv.z + xv.w * vv.w;
        }
        float pz = q * Wg[(size_t)r * 1280 + c * 128 + o * 8 + i];
        #pragma unroll
        for (int msk = 32; msk > 0; msk >>= 1) pz += __shfl_xor(pz, msk, 64);
        if ((t & 63) == 0) red2[t >> 6] = pz;
        __syncthreads();
        if (t < 2) {
            float d = red2[t * 2] + red2[t * 2 + 1];
            float* dst = ws + WS_BCOL + c * R + (rbase + m * 2 + t);
            float val = d * (1.0f / B);
            if (it == 0) *dst = val; else *dst += val;
        }
    }
}

// ---------- OUT: final squash (blocks 0..99) + c_full + bulk stream units ----------
__global__ __launch_bounds__(256) void k_out(const float* __restrict__ x0,
                                             const float* __restrict__ x1,
                                             const float* __restrict__ x2,
                                             float* __restrict__ ws,
                                             const float* __restrict__ Wg,
                                             float4* __restrict__ out) {
    const int bid = blockIdx.x, t = threadIdx.x;
    if (bid < B) {   // final squash from G2 partials -> v_j + s_mut straight to out
        const int b = bid;
        __shared__ float sl[160];
        __shared__ float nf[C];
        __shared__ __align__(16) float vv[160];
        __shared__ __align__(16) float sm[160];
        if (t < 160) {
            int c = t >> 4, o = t & 15;
            float s = 0.f;
            const float* p = ws + WS_PART + ((size_t)c * NRC * B + b) * 16 + o;
            #pragma unroll 8
            for (int rc = 0; rc < NRC; rc++) s += p[rc * 1600];
            sl[t] = s;
        }
        __syncthreads();
        if (t < C) {
            float fv[C];
            #pragma unroll
            for (int c2 = 0; c2 < C; c2++) fv[c2] = sl[c2 * O];
            float mine = sl[t * O];
            int rank = 0, i1 = 0, i2 = 0, i3 = 0;
            #pragma unroll
            for (int c2 = 0; c2 < C; c2++) {
                rank += (fv[c2] < mine) || (fv[c2] == mine && c2 < t);
                i1 += fv[c2] < T1c;
                i2 += fv[c2] < 0.0f;
                i3 += fv[c2] < T3c;
            }
            float nv = mine;
            if (i1 > 0 && rank < i1 - 1)                               nv = -0.074520095f * mine + 0.349297946f;
            else if (i2 > 0 && i2 > i1 && rank >= i1 && rank < i2 - 1) nv = -0.534473989f * mine + 0.27196494f;
            else if (i3 > 0 && i3 > i2 && rank >= i2 && rank < i3 - 1) nv = 0.637642944f * mine + 0.295330779f;
            else if (i3 < C && rank >= i3 && rank < C - 1)             nv = 0.169344703f * mine + 0.353784456f;
            nf[t] = nv;
        }
        __syncthreads();
        if (t < 160) {
            int c = t >> 4, o = t & 15;
            float smut = (o == 0) ? nf[c] : sl[t];
            sm[t] = smut;
            vv[t] = nf[c] * smut;
        }
        __syncthreads();
        if (t < 40) {
            nt_store4(((const float4*)vv)[t], &out[O_VJ + b * 40 + t]);
            nt_store4(((const float4*)sm)[t], &out[O_SM + b * 40 + t]);
        }
    }
    // c_full (CSM repeated per b)
    const float4* cs4 = (const float4*)(ws + WS_CSM);
    for (int j = bid * 256 + t; j < 288000; j += 2048 * 256)
        nt_store4(cs4[j % 2880], &out[O_CF + j]);
    // remaining stream units (4080..7824)
    for (int k = 0; k < 2; k++) {
        int u = 4080 + bid + k * 2048;
        if (u < U_TOT)
            stream_unit(u, (const float4*)Wg, (const float4*)x0,
                        (const float4*)x1, (const float4*)x2, out);
    }
}

extern "C" void kernel_launch(void* const* d_in, const int* in_sizes, int n_in,
                              void* d_out, int out_size, void* d_ws, size_t ws_size,
                              hipStream_t stream) {
    (void)in_sizes; (void)n_in; (void)out_size; (void)ws_size;
    const float* x0 = (const float*)d_in[0];
    const float* x1 = (const float*)d_in[1];
    const float* x2 = (const float*)d_in[2];
    const float* Wg = (const float*)d_in[3];
    const float4* x14 = (const float4*)x1;
    const float4* x24 = (const float4*)x2;
    float* ws = (float*)d_ws;
    float4* out = (float4*)d_out;

    // 6 launches, 5 boundaries. A' = 720 work blocks + 900 riders (17KB LDS,
    // 8 blocks/CU -> 2048 resident, single round). G 39KB LDS -> 4/CU -> 1024.
    // unit bases: G0=0(760) A0=760(900) G1=1660(760) A1=2420(900) G2=3320(760);
    // k_out drains 4080..7824.
    hipLaunchKernelGGL(k_gemm,  dim3(240 + 760), dim3(256), 0, stream, Wg, x0, ws, x14, x24, out, 0, 0);
    hipLaunchKernelGGL(k_agree, dim3(720 + 900), dim3(256), 0, stream, Wg, x0, ws, x14, x24, out, 0, 760);
    hipLaunchKernelGGL(k_gemm,  dim3(240 + 760), dim3(256), 0, stream, Wg, x0, ws, x14, x24, out, 1, 1660);
    hipLaunchKernelGGL(k_agree, dim3(720 + 900), dim3(256), 0, stream, Wg, x0, ws, x14, x24, out, 1, 2420);
    hipLaunchKernelGGL(k_gemm,  dim3(240 + 760), dim3(256), 0, stream, Wg, x0, ws, x14, x24, out, 2, 3320);
    hipLaunchKernelGGL(k_out,   dim3(2048), dim3(256), 0, stream, x0, x1, x2, ws, Wg, out);
}